// Round 6
// baseline (16928.775 us; speedup 1.0000x reference)
//
#include <hip/hip_runtime.h>
#include <hip/hip_bf16.h>

#define T_TOTAL 1024
#define BATCH   64
#define HID     512

__device__ __forceinline__ float fast_sigmoid(float x) {
    return 1.f / (1.f + __expf(-x));
}
__device__ __forceinline__ float fast_tanh(float x) {
    float ax = fabsf(x);
    float e  = __expf(-2.f * ax);
    float t  = (1.f - e) / (1.f + e);
    return copysignf(t, x);
}

// ---------------------------------------------------------------------------
// GEMM: C[m,n] = sum_k A[rowg(m),k] * W[n,k] + bias[n]
// A row-major [*, K], W row-major [N, K] (i.e. computes A @ W^T + bias).
// ---------------------------------------------------------------------------
template<int BM, int BN, int TM, int TN>
__global__ __launch_bounds__(256, 2)
void gemm_bt_k(const float* __restrict__ A, const float* __restrict__ W,
               const float* __restrict__ bias, float* __restrict__ C,
               int K, int T, int Tc, int t0, int N)
{
    constexpr int BK = 16;
    constexpr int WSTR = BN + (BN / 32) * 4;
    static_assert(BM / TM == 16 && BN / TN == 16, "256 threads required");
    __shared__ float As[BK][BM + 4];
    __shared__ float Ws[BK][WSTR];

    const int tid = threadIdx.x;
    const int tx  = tid & 15;
    const int ty  = tid >> 4;
    const int m0  = blockIdx.y * BM;
    const int n0  = blockIdx.x * BN;
    const int nA  = tx * TN;
    const int nsw = nA + ((nA >> 5) << 2);

    float acc[TM][TN];
#pragma unroll
    for (int i = 0; i < TM; ++i)
#pragma unroll
        for (int j = 0; j < TN; ++j) acc[i][j] = 0.f;

    for (int k0 = 0; k0 < K; k0 += BK) {
#pragma unroll
        for (int i = 0; i < (BM * BK) / 1024; ++i) {
            int id = tid + (i << 8);
            int m  = id >> 2;
            int kq = (id & 3) << 2;
            int mloc = m0 + m;
            int rowg = (mloc / Tc) * T + t0 + (mloc % Tc);
            const float4 v = *reinterpret_cast<const float4*>(A + (size_t)rowg * K + k0 + kq);
            As[kq + 0][m] = v.x; As[kq + 1][m] = v.y;
            As[kq + 2][m] = v.z; As[kq + 3][m] = v.w;
        }
#pragma unroll
        for (int i = 0; i < (BN * BK) / 1024; ++i) {
            int id = tid + (i << 8);
            int n  = id >> 2;
            int kq = (id & 3) << 2;
            const float4 v = *reinterpret_cast<const float4*>(W + (size_t)(n0 + n) * K + k0 + kq);
            int np = n + ((n >> 5) << 2);
            Ws[kq + 0][np] = v.x; Ws[kq + 1][np] = v.y;
            Ws[kq + 2][np] = v.z; Ws[kq + 3][np] = v.w;
        }
        __syncthreads();
#pragma unroll
        for (int k = 0; k < BK; ++k) {
            float a[TM], b[TN];
#pragma unroll
            for (int i = 0; i < TM; i += 4)
                *reinterpret_cast<float4*>(&a[i]) =
                    *reinterpret_cast<const float4*>(&As[k][ty * TM + i]);
#pragma unroll
            for (int j = 0; j < TN; j += 4)
                *reinterpret_cast<float4*>(&b[j]) =
                    *reinterpret_cast<const float4*>(&Ws[k][nsw + j]);
#pragma unroll
            for (int i = 0; i < TM; ++i)
#pragma unroll
                for (int j = 0; j < TN; ++j)
                    acc[i][j] = fmaf(a[i], b[j], acc[i][j]);
        }
        __syncthreads();
    }
#pragma unroll
    for (int i = 0; i < TM; ++i) {
        const size_t crow = (size_t)(m0 + ty * TM + i) * N + n0 + nA;
#pragma unroll
        for (int j = 0; j < TN; j += 4) {
            float4 bv = *reinterpret_cast<const float4*>(bias + n0 + nA + j);
            float4 v;
            v.x = acc[i][j + 0] + bv.x; v.y = acc[i][j + 1] + bv.y;
            v.z = acc[i][j + 2] + bv.z; v.w = acc[i][j + 3] + bv.w;
            *reinterpret_cast<float4*>(C + crow + j) = v;
        }
    }
}

// ---------------------------------------------------------------------------
// Persistent GRU scan (one T-chunk of one layer).
// Topology: 16 groups x 16 blocks x 512 threads; group owns 4 batch rows,
// block owns 32 h-dims (R4). R5 restructure:
//   - thread = (wave w, kc = lane>>2, dl = lane&3), d = 4w+dl: all 16
//     K-chunk partials of an output live in ONE wave -> reduce via 4
//     __shfl_xor steps, no part-LDS, no reduce barriers.
//   - ONE __syncthreads per step (after h staging). Gates on lanes<16
//     (one output each: b = lane>>2).
//   - poll backoff: first miss sleeps long (arrival is ~1 step away),
//     then tight rounds -> ~8x less L2 atomic-load storm.
// Tagged-word exchange protocol unchanged (relaxed agent atomics, 2-slot
// hbuf, overwrite-safe by induction; tags unique per layer+step).
// Single-barrier skew safety: a wave stages t+1 (buffer (t+1)&1) only after
// passing barrier t, which implies all waves finished step t-1's reads of
// that buffer.
// ---------------------------------------------------------------------------
__global__ __launch_bounds__(512, 2)
void gru_scan(const float* __restrict__ xg,    // chunk-local [64][Tc][1536]
              const float* __restrict__ w_hh,  // [1536][512]
              const float* __restrict__ b_hh,  // [1536]
              float* __restrict__ y,           // [64][1024][512]
              unsigned long long* __restrict__ hbuf, // [16 grp][2 slot][4 b][512]
              int t0, int Tc, int tagbase)
{
    const int tid  = threadIdx.x;
    const int grp  = blockIdx.x & 15;     // same XCD under mod-8 round-robin
    const int os   = blockIdx.x >> 4;     // output slice 0..15
    const int D0   = os << 5;             // 32 h-dims per block
    const int w    = tid >> 6;            // wave 0..7
    const int lane = tid & 63;
    const int kc   = lane >> 2;           // K-chunk 0..15 (within wave)
    const int dl   = lane & 3;
    const int d    = (w << 2) + dl;       // block-local dim 0..31
    const int bg   = grp << 2;            // 4 batch rows per group

    __shared__ float h_lds[2][4 * 576];   // [slot][b][D>>5][36] padded

    // persistent weights: w4[g][j] = w_hh[g*512+D0+d][kc*32 + 4j ..]
    float4 w4[3][8];
#pragma unroll
    for (int g = 0; g < 3; ++g) {
        const float* wr = w_hh + (size_t)(g * 512 + D0 + d) * 512 + kc * 32;
#pragma unroll
        for (int j = 0; j < 8; ++j)
            w4[g][j] = *reinterpret_cast<const float4*>(wr + (j << 2));
    }
    float bias_g[3];
#pragma unroll
    for (int g = 0; g < 3; ++g) bias_g[g] = b_hh[g * 512 + D0 + d];

    const bool is_gate = (lane < 16);     // 16 gate lanes/wave: b = kc(0..3)
    const int  gb = kc & 3;               // gate lane's batch row

    for (int tl = 0; tl < Tc; ++tl) {
        const int tg = t0 + tl;
        float* hl = h_lds[tl & 1];

        // gate lanes prefetch this step's xg early (hidden behind the poll)
        float xr = 0.f, xz = 0.f, xn = 0.f;
        if (is_gate) {
            const size_t rowo = ((size_t)(bg + gb) * Tc + tl) * 1536 + D0 + d;
            xr = xg[rowo];
            xz = xg[rowo + 512];
            xn = xg[rowo + 1024];
        }

        // stage h_{t-1}[4][512] into LDS: thread owns D=tid for b=0..3
        if (tg == 0) {
#pragma unroll
            for (int i = 0; i < 4; ++i)
                hl[i * 576 + (tid >> 5) * 36 + (tid & 31)] = 0.f;
        } else {
            const unsigned long long* hsrc =
                hbuf + (size_t)(grp * 2 + ((tg - 1) & 1)) * 2048;
            const unsigned int tagexp = (unsigned int)(tagbase + tl - 1);
            unsigned long long v[4];
            unsigned int pend = 0xFu;
            bool first = true;
            while (pend) {
#pragma unroll
                for (int i = 0; i < 4; ++i)
                    if (pend & (1u << i))
                        v[i] = __hip_atomic_load(hsrc + tid + (i << 9),
                                __ATOMIC_RELAXED, __HIP_MEMORY_SCOPE_AGENT);
#pragma unroll
                for (int i = 0; i < 4; ++i)
                    if ((pend & (1u << i)) &&
                        (unsigned int)(v[i] >> 32) == tagexp) {
                        union { unsigned int u; float f; } cv;
                        cv.u = (unsigned int)v[i];
                        hl[i * 576 + (tid >> 5) * 36 + (tid & 31)] = cv.f;
                        pend &= ~(1u << i);
                    }
                if (pend) {
                    if (first) { __builtin_amdgcn_s_sleep(32); first = false; }
                    else       { __builtin_amdgcn_s_sleep(2); }
                }
            }
        }
        __syncthreads();   // the ONLY barrier per step

        // register MAC: acc[g][b] over this thread's 32-wide K chunk.
        // 4 lanes (dl) share kc -> LDS broadcast; kc pattern <=2-way (free).
        float acc[3][4];
#pragma unroll
        for (int g = 0; g < 3; ++g)
#pragma unroll
            for (int b = 0; b < 4; ++b) acc[g][b] = 0.f;
        const float* hb_base = hl + kc * 36;
#pragma unroll
        for (int j = 0; j < 8; ++j) {
            float4 h4[4];
#pragma unroll
            for (int b = 0; b < 4; ++b)
                h4[b] = *reinterpret_cast<const float4*>(hb_base + b * 576 + (j << 2));
#pragma unroll
            for (int g = 0; g < 3; ++g) {
                const float4 wv = w4[g][j];
#pragma unroll
                for (int b = 0; b < 4; ++b) {
                    acc[g][b] = fmaf(wv.x, h4[b].x, acc[g][b]);
                    acc[g][b] = fmaf(wv.y, h4[b].y, acc[g][b]);
                    acc[g][b] = fmaf(wv.z, h4[b].z, acc[g][b]);
                    acc[g][b] = fmaf(wv.w, h4[b].w, acc[g][b]);
                }
            }
        }

        // wave-local butterfly all-reduce over the 16 kc lanes (stride 4)
#pragma unroll
        for (int m = 4; m <= 32; m <<= 1)
#pragma unroll
            for (int g = 0; g < 3; ++g)
#pragma unroll
                for (int b = 0; b < 4; ++b)
                    acc[g][b] += __shfl_xor(acc[g][b], m, 64);

        // gates + state update + tagged publish (fire-and-forget)
        if (is_gate) {
            const float hr = acc[0][gb] + bias_g[0];
            const float hz = acc[1][gb] + bias_g[1];
            const float hn = acc[2][gb] + bias_g[2];
            const int D = D0 + d;
            const float hp = hl[gb * 576 + (D >> 5) * 36 + (D & 31)];
            const float r = fast_sigmoid(xr + hr);
            const float z = fast_sigmoid(xz + hz);
            const float nv = fast_tanh(xn + r * hn);
            const float h = (1.f - z) * nv + z * hp;
            y[((size_t)(bg + gb) * T_TOTAL + tg) * HID + D] = h;
            union { float f; unsigned int u; } cv; cv.f = h;
            const unsigned long long pk =
                ((unsigned long long)(unsigned int)(tagbase + tl) << 32) | cv.u;
            unsigned long long* hdst =
                hbuf + (size_t)(grp * 2 + (tg & 1)) * 2048 + gb * 512 + D;
            __hip_atomic_store(hdst, pk, __ATOMIC_RELAXED,
                               __HIP_MEMORY_SCOPE_AGENT);
        }
        // no trailing barrier: next iter stages into the other h_lds buffer.
    }
}

// ---------------------------------------------------------------------------
extern "C" void kernel_launch(void* const* d_in, const int* in_sizes, int n_in,
                              void* d_out, int out_size, void* d_ws, size_t ws_size,
                              hipStream_t stream)
{
    const float* x       = (const float*)d_in[0];
    const float* w_ih[2] = {(const float*)d_in[1], (const float*)d_in[5]};
    const float* w_hh[2] = {(const float*)d_in[2], (const float*)d_in[6]};
    const float* b_ih[2] = {(const float*)d_in[3], (const float*)d_in[7]};
    const float* b_hh[2] = {(const float*)d_in[4], (const float*)d_in[8]};
    const float* fc_w    = (const float*)d_in[9];
    const float* fc_b    = (const float*)d_in[10];
    float* out = (float*)d_out;

    const size_t Y_BYTES = (size_t)BATCH * T_TOTAL * HID * 4;   // 128 MiB
    const size_t H_BYTES = (size_t)16 * 2 * 4 * 512 * 8;        // 512 KiB (u64)
    int Tc = 256;
    while (Tc > 32) {
        size_t need = (size_t)BATCH * Tc * 1536 * 4 + Y_BYTES + H_BYTES;
        if (need <= ws_size) break;
        Tc >>= 1;
    }

    char* p = (char*)d_ws;
    float* xg_buf = (float*)p;                 p += (size_t)BATCH * Tc * 1536 * 4;
    float* y_buf  = (float*)p;                 p += Y_BYTES;
    unsigned long long* hbuf = (unsigned long long*)p;

    const int nchunks = T_TOTAL / Tc;
    for (int L = 0; L < 2; ++L) {
        const float* A = L ? y_buf : x;
        const int K    = L ? HID : 64;
        for (int c = 0; c < nchunks; ++c) {
            dim3 g1(1536 / 128, (BATCH * Tc) / 128);
            gemm_bt_k<128, 128, 8, 8><<<g1, 256, 0, stream>>>(
                A, w_ih[L], b_ih[L], xg_buf, K, T_TOTAL, Tc, c * Tc, 1536);
            gru_scan<<<256, 512, 0, stream>>>(
                xg_buf, w_hh[L], b_hh[L], y_buf, hbuf,
                c * Tc, Tc, (L << 11) + c * Tc);
        }
    }
    dim3 g2(64 / 64, (BATCH * T_TOTAL) / 128);
    gemm_bt_k<128, 64, 8, 4><<<g2, 256, 0, stream>>>(
        y_buf, fc_w, fc_b, out, HID, BATCH * T_TOTAL, BATCH * T_TOTAL, 0, 64);
}

// Round 7
// 11762.923 us; speedup vs baseline: 1.4392x; 1.4392x over previous
//
#include <hip/hip_runtime.h>
#include <hip/hip_bf16.h>

#define T_TOTAL 1024
#define BATCH   64
#define HID     512

__device__ __forceinline__ float fast_sigmoid(float x) {
    return 1.f / (1.f + __expf(-x));
}
__device__ __forceinline__ float fast_tanh(float x) {
    float ax = fabsf(x);
    float e  = __expf(-2.f * ax);
    float t  = (1.f - e) / (1.f + e);
    return copysignf(t, x);
}

// ---------------------------------------------------------------------------
// GEMM: C[m,n] = sum_k A[rowg(m),k] * W[n,k] + bias[n]
// A row-major [*, K], W row-major [N, K] (i.e. computes A @ W^T + bias).
// ---------------------------------------------------------------------------
template<int BM, int BN, int TM, int TN>
__global__ __launch_bounds__(256, 2)
void gemm_bt_k(const float* __restrict__ A, const float* __restrict__ W,
               const float* __restrict__ bias, float* __restrict__ C,
               int K, int T, int Tc, int t0, int N)
{
    constexpr int BK = 16;
    constexpr int WSTR = BN + (BN / 32) * 4;
    static_assert(BM / TM == 16 && BN / TN == 16, "256 threads required");
    __shared__ float As[BK][BM + 4];
    __shared__ float Ws[BK][WSTR];

    const int tid = threadIdx.x;
    const int tx  = tid & 15;
    const int ty  = tid >> 4;
    const int m0  = blockIdx.y * BM;
    const int n0  = blockIdx.x * BN;
    const int nA  = tx * TN;
    const int nsw = nA + ((nA >> 5) << 2);

    float acc[TM][TN];
#pragma unroll
    for (int i = 0; i < TM; ++i)
#pragma unroll
        for (int j = 0; j < TN; ++j) acc[i][j] = 0.f;

    for (int k0 = 0; k0 < K; k0 += BK) {
#pragma unroll
        for (int i = 0; i < (BM * BK) / 1024; ++i) {
            int id = tid + (i << 8);
            int m  = id >> 2;
            int kq = (id & 3) << 2;
            int mloc = m0 + m;
            int rowg = (mloc / Tc) * T + t0 + (mloc % Tc);
            const float4 v = *reinterpret_cast<const float4*>(A + (size_t)rowg * K + k0 + kq);
            As[kq + 0][m] = v.x; As[kq + 1][m] = v.y;
            As[kq + 2][m] = v.z; As[kq + 3][m] = v.w;
        }
#pragma unroll
        for (int i = 0; i < (BN * BK) / 1024; ++i) {
            int id = tid + (i << 8);
            int n  = id >> 2;
            int kq = (id & 3) << 2;
            const float4 v = *reinterpret_cast<const float4*>(W + (size_t)(n0 + n) * K + k0 + kq);
            int np = n + ((n >> 5) << 2);
            Ws[kq + 0][np] = v.x; Ws[kq + 1][np] = v.y;
            Ws[kq + 2][np] = v.z; Ws[kq + 3][np] = v.w;
        }
        __syncthreads();
#pragma unroll
        for (int k = 0; k < BK; ++k) {
            float a[TM], b[TN];
#pragma unroll
            for (int i = 0; i < TM; i += 4)
                *reinterpret_cast<float4*>(&a[i]) =
                    *reinterpret_cast<const float4*>(&As[k][ty * TM + i]);
#pragma unroll
            for (int j = 0; j < TN; j += 4)
                *reinterpret_cast<float4*>(&b[j]) =
                    *reinterpret_cast<const float4*>(&Ws[k][nsw + j]);
#pragma unroll
            for (int i = 0; i < TM; ++i)
#pragma unroll
                for (int j = 0; j < TN; ++j)
                    acc[i][j] = fmaf(a[i], b[j], acc[i][j]);
        }
        __syncthreads();
    }
#pragma unroll
    for (int i = 0; i < TM; ++i) {
        const size_t crow = (size_t)(m0 + ty * TM + i) * N + n0 + nA;
#pragma unroll
        for (int j = 0; j < TN; j += 4) {
            float4 bv = *reinterpret_cast<const float4*>(bias + n0 + nA + j);
            float4 v;
            v.x = acc[i][j + 0] + bv.x; v.y = acc[i][j + 1] + bv.y;
            v.z = acc[i][j + 2] + bv.z; v.w = acc[i][j + 3] + bv.w;
            *reinterpret_cast<float4*>(C + crow + j) = v;
        }
    }
}

// ---------------------------------------------------------------------------
// Persistent GRU scan (one T-chunk of one layer).
// Topology: 16 groups x 16 blocks x 512 threads; group owns 4 batch rows,
// block owns 32 h-dims. R7 = R4-proven pieces + R5's butterfly:
//   - thread map (w, kc=lane>>2, dl=lane&3), d=4w+dl: all 16 K-chunk
//     partials of an output in ONE wave -> 4 __shfl_xor steps, no part-LDS.
//   - TIGHT poll, s_sleep(1) only (R6's 2048-cyc backoff quantized the
//     per-step max-of-16-blocks detect delay -> 2.2x regression).
//   - COALESCED publish: gate lanes route h through 128-float LDS; after a
//     2nd barrier, tid<128 issues contiguous 256B hbuf atomic bursts + y
//     stores (R5's scattered 32B clusters lengthened the relay tail).
// Tagged-word exchange unchanged (relaxed agent atomics, 2-slot hbuf,
// overwrite-safe by induction; tags unique per layer+step; 0xAA poison
// never matches). 2-slot h_lds reuse safe: staging buf (t+1)&1 starts only
// after barrier#2(t) -> all waves passed barrier#1(t) -> step t-1 MAC done.
// ---------------------------------------------------------------------------
__global__ __launch_bounds__(512, 2)
void gru_scan(const float* __restrict__ xg,    // chunk-local [64][Tc][1536]
              const float* __restrict__ w_hh,  // [1536][512]
              const float* __restrict__ b_hh,  // [1536]
              float* __restrict__ y,           // [64][1024][512]
              unsigned long long* __restrict__ hbuf, // [16 grp][2 slot][4 b][512]
              int t0, int Tc, int tagbase)
{
    const int tid  = threadIdx.x;
    const int grp  = blockIdx.x & 15;     // same XCD under mod-8 round-robin
    const int os   = blockIdx.x >> 4;     // output slice 0..15
    const int D0   = os << 5;             // 32 h-dims per block
    const int w    = tid >> 6;            // wave 0..7
    const int lane = tid & 63;
    const int kc   = lane >> 2;           // K-chunk 0..15 (within wave)
    const int dl   = lane & 3;
    const int d    = (w << 2) + dl;       // block-local dim 0..31
    const int bg   = grp << 2;            // 4 batch rows per group

    __shared__ float h_lds[2][4 * 576];   // [slot][b][D>>5][36] padded
    __shared__ float hout[128];           // [b][32] new-h routing buffer

    // persistent weights: w4[g][j] = w_hh[g*512+D0+d][kc*32 + 4j ..]
    float4 w4[3][8];
#pragma unroll
    for (int g = 0; g < 3; ++g) {
        const float* wr = w_hh + (size_t)(g * 512 + D0 + d) * 512 + kc * 32;
#pragma unroll
        for (int j = 0; j < 8; ++j)
            w4[g][j] = *reinterpret_cast<const float4*>(wr + (j << 2));
    }
    float bias_g[3];
#pragma unroll
    for (int g = 0; g < 3; ++g) bias_g[g] = b_hh[g * 512 + D0 + d];

    const bool is_gate = (lane < 16);     // 16 gate lanes/wave: b = kc(0..3)
    const int  gb = kc & 3;               // gate lane's batch row

    for (int tl = 0; tl < Tc; ++tl) {
        const int tg = t0 + tl;
        float* hl = h_lds[tl & 1];

        // gate lanes prefetch this step's xg early (hidden behind the poll)
        float xr = 0.f, xz = 0.f, xn = 0.f;
        if (is_gate) {
            const size_t rowo = ((size_t)(bg + gb) * Tc + tl) * 1536 + D0 + d;
            xr = xg[rowo];
            xz = xg[rowo + 512];
            xn = xg[rowo + 1024];
        }

        // stage h_{t-1}[4][512] into LDS: thread owns D=tid for b=0..3
        if (tg == 0) {
#pragma unroll
            for (int i = 0; i < 4; ++i)
                hl[i * 576 + (tid >> 5) * 36 + (tid & 31)] = 0.f;
        } else {
            const unsigned long long* hsrc =
                hbuf + (size_t)(grp * 2 + ((tg - 1) & 1)) * 2048;
            const unsigned int tagexp = (unsigned int)(tagbase + tl - 1);
            unsigned long long v[4];
            unsigned int pend = 0xFu;
            while (pend) {
#pragma unroll
                for (int i = 0; i < 4; ++i)
                    if (pend & (1u << i))
                        v[i] = __hip_atomic_load(hsrc + tid + (i << 9),
                                __ATOMIC_RELAXED, __HIP_MEMORY_SCOPE_AGENT);
#pragma unroll
                for (int i = 0; i < 4; ++i)
                    if ((pend & (1u << i)) &&
                        (unsigned int)(v[i] >> 32) == tagexp) {
                        union { unsigned int u; float f; } cv;
                        cv.u = (unsigned int)v[i];
                        hl[i * 576 + (tid >> 5) * 36 + (tid & 31)] = cv.f;
                        pend &= ~(1u << i);
                    }
                if (pend) __builtin_amdgcn_s_sleep(1);
            }
        }
        __syncthreads();   // barrier #1: h_{t-1} staged

        // register MAC: acc[g][b] over this thread's 32-wide K chunk.
        float acc[3][4];
#pragma unroll
        for (int g = 0; g < 3; ++g)
#pragma unroll
            for (int b = 0; b < 4; ++b) acc[g][b] = 0.f;
        const float* hb_base = hl + kc * 36;
#pragma unroll
        for (int j = 0; j < 8; ++j) {
            float4 h4[4];
#pragma unroll
            for (int b = 0; b < 4; ++b)
                h4[b] = *reinterpret_cast<const float4*>(hb_base + b * 576 + (j << 2));
#pragma unroll
            for (int g = 0; g < 3; ++g) {
                const float4 wv = w4[g][j];
#pragma unroll
                for (int b = 0; b < 4; ++b) {
                    acc[g][b] = fmaf(wv.x, h4[b].x, acc[g][b]);
                    acc[g][b] = fmaf(wv.y, h4[b].y, acc[g][b]);
                    acc[g][b] = fmaf(wv.z, h4[b].z, acc[g][b]);
                    acc[g][b] = fmaf(wv.w, h4[b].w, acc[g][b]);
                }
            }
        }

        // wave-local butterfly all-reduce over the 16 kc lanes (stride 4)
#pragma unroll
        for (int m = 4; m <= 32; m <<= 1)
#pragma unroll
            for (int g = 0; g < 3; ++g)
#pragma unroll
                for (int b = 0; b < 4; ++b)
                    acc[g][b] += __shfl_xor(acc[g][b], m, 64);

        // gates on lane<16 of each wave; route new h through LDS
        if (is_gate) {
            const float hr = acc[0][gb] + bias_g[0];
            const float hz = acc[1][gb] + bias_g[1];
            const float hn = acc[2][gb] + bias_g[2];
            const float hp = hl[gb * 576 + os * 36 + d];
            const float r = fast_sigmoid(xr + hr);
            const float z = fast_sigmoid(xz + hz);
            const float nv = fast_tanh(xn + r * hn);
            hout[gb * 32 + d] = (1.f - z) * nv + z * hp;
        }
        __syncthreads();   // barrier #2: hout complete

        // coalesced publish by waves 0-1: contiguous 256B bursts per row.
        // hbuf atomic FIRST (relay critical path), y store second.
        if (tid < 128) {
            const int pb = tid >> 5;          // batch row 0..3
            const int pd = tid & 31;          // dim 0..31
            const float h = hout[tid];
            union { float f; unsigned int u; } cv; cv.f = h;
            const unsigned long long pk =
                ((unsigned long long)(unsigned int)(tagbase + tl) << 32) | cv.u;
            unsigned long long* hdst =
                hbuf + (size_t)(grp * 2 + (tg & 1)) * 2048 + pb * 512 + D0 + pd;
            __hip_atomic_store(hdst, pk, __ATOMIC_RELAXED,
                               __HIP_MEMORY_SCOPE_AGENT);
            y[((size_t)(bg + pb) * T_TOTAL + tg) * HID + D0 + pd] = h;
        }
        // no trailing barrier: next iter stages into the other h_lds buffer;
        // hout(t+1) writes happen only after all threads pass barrier#1(t+1).
    }
}

// ---------------------------------------------------------------------------
extern "C" void kernel_launch(void* const* d_in, const int* in_sizes, int n_in,
                              void* d_out, int out_size, void* d_ws, size_t ws_size,
                              hipStream_t stream)
{
    const float* x       = (const float*)d_in[0];
    const float* w_ih[2] = {(const float*)d_in[1], (const float*)d_in[5]};
    const float* w_hh[2] = {(const float*)d_in[2], (const float*)d_in[6]};
    const float* b_ih[2] = {(const float*)d_in[3], (const float*)d_in[7]};
    const float* b_hh[2] = {(const float*)d_in[4], (const float*)d_in[8]};
    const float* fc_w    = (const float*)d_in[9];
    const float* fc_b    = (const float*)d_in[10];
    float* out = (float*)d_out;

    const size_t Y_BYTES = (size_t)BATCH * T_TOTAL * HID * 4;   // 128 MiB
    const size_t H_BYTES = (size_t)16 * 2 * 4 * 512 * 8;        // 512 KiB (u64)
    int Tc = 256;
    while (Tc > 32) {
        size_t need = (size_t)BATCH * Tc * 1536 * 4 + Y_BYTES + H_BYTES;
        if (need <= ws_size) break;
        Tc >>= 1;
    }

    char* p = (char*)d_ws;
    float* xg_buf = (float*)p;                 p += (size_t)BATCH * Tc * 1536 * 4;
    float* y_buf  = (float*)p;                 p += Y_BYTES;
    unsigned long long* hbuf = (unsigned long long*)p;

    const int nchunks = T_TOTAL / Tc;
    for (int L = 0; L < 2; ++L) {
        const float* A = L ? y_buf : x;
        const int K    = L ? HID : 64;
        for (int c = 0; c < nchunks; ++c) {
            dim3 g1(1536 / 128, (BATCH * Tc) / 128);
            gemm_bt_k<128, 128, 8, 8><<<g1, 256, 0, stream>>>(
                A, w_ih[L], b_ih[L], xg_buf, K, T_TOTAL, Tc, c * Tc, 1536);
            gru_scan<<<256, 512, 0, stream>>>(
                xg_buf, w_hh[L], b_hh[L], y_buf, hbuf,
                c * Tc, Tc, (L << 11) + c * Tc);
        }
    }
    dim3 g2(64 / 64, (BATCH * T_TOTAL) / 128);
    gemm_bt_k<128, 64, 8, 4><<<g2, 256, 0, stream>>>(
        y_buf, fc_w, fc_b, out, HID, BATCH * T_TOTAL, BATCH * T_TOTAL, 0, 64);
}

// Round 8
// 6952.152 us; speedup vs baseline: 2.4350x; 1.6920x over previous
//
#include <hip/hip_runtime.h>
#include <hip/hip_bf16.h>

#define T_TOTAL 1024
#define BATCH   64
#define HID     512

__device__ __forceinline__ float fast_sigmoid(float x) {
    return 1.f / (1.f + __expf(-x));
}
__device__ __forceinline__ float fast_tanh(float x) {
    float ax = fabsf(x);
    float e  = __expf(-2.f * ax);
    float t  = (1.f - e) / (1.f + e);
    return copysignf(t, x);
}

// ---------------------------------------------------------------------------
// GEMM: C[m,n] = sum_k A[rowg(m),k] * W[n,k] + bias[n]
// A row-major [*, K], W row-major [N, K] (i.e. computes A @ W^T + bias).
// ---------------------------------------------------------------------------
template<int BM, int BN, int TM, int TN>
__global__ __launch_bounds__(256, 2)
void gemm_bt_k(const float* __restrict__ A, const float* __restrict__ W,
               const float* __restrict__ bias, float* __restrict__ C,
               int K, int T, int Tc, int t0, int N)
{
    constexpr int BK = 16;
    constexpr int WSTR = BN + (BN / 32) * 4;
    static_assert(BM / TM == 16 && BN / TN == 16, "256 threads required");
    __shared__ float As[BK][BM + 4];
    __shared__ float Ws[BK][WSTR];

    const int tid = threadIdx.x;
    const int tx  = tid & 15;
    const int ty  = tid >> 4;
    const int m0  = blockIdx.y * BM;
    const int n0  = blockIdx.x * BN;
    const int nA  = tx * TN;
    const int nsw = nA + ((nA >> 5) << 2);

    float acc[TM][TN];
#pragma unroll
    for (int i = 0; i < TM; ++i)
#pragma unroll
        for (int j = 0; j < TN; ++j) acc[i][j] = 0.f;

    for (int k0 = 0; k0 < K; k0 += BK) {
#pragma unroll
        for (int i = 0; i < (BM * BK) / 1024; ++i) {
            int id = tid + (i << 8);
            int m  = id >> 2;
            int kq = (id & 3) << 2;
            int mloc = m0 + m;
            int rowg = (mloc / Tc) * T + t0 + (mloc % Tc);
            const float4 v = *reinterpret_cast<const float4*>(A + (size_t)rowg * K + k0 + kq);
            As[kq + 0][m] = v.x; As[kq + 1][m] = v.y;
            As[kq + 2][m] = v.z; As[kq + 3][m] = v.w;
        }
#pragma unroll
        for (int i = 0; i < (BN * BK) / 1024; ++i) {
            int id = tid + (i << 8);
            int n  = id >> 2;
            int kq = (id & 3) << 2;
            const float4 v = *reinterpret_cast<const float4*>(W + (size_t)(n0 + n) * K + k0 + kq);
            int np = n + ((n >> 5) << 2);
            Ws[kq + 0][np] = v.x; Ws[kq + 1][np] = v.y;
            Ws[kq + 2][np] = v.z; Ws[kq + 3][np] = v.w;
        }
        __syncthreads();
#pragma unroll
        for (int k = 0; k < BK; ++k) {
            float a[TM], b[TN];
#pragma unroll
            for (int i = 0; i < TM; i += 4)
                *reinterpret_cast<float4*>(&a[i]) =
                    *reinterpret_cast<const float4*>(&As[k][ty * TM + i]);
#pragma unroll
            for (int j = 0; j < TN; j += 4)
                *reinterpret_cast<float4*>(&b[j]) =
                    *reinterpret_cast<const float4*>(&Ws[k][nsw + j]);
#pragma unroll
            for (int i = 0; i < TM; ++i)
#pragma unroll
                for (int j = 0; j < TN; ++j)
                    acc[i][j] = fmaf(a[i], b[j], acc[i][j]);
        }
        __syncthreads();
    }
#pragma unroll
    for (int i = 0; i < TM; ++i) {
        const size_t crow = (size_t)(m0 + ty * TM + i) * N + n0 + nA;
#pragma unroll
        for (int j = 0; j < TN; j += 4) {
            float4 bv = *reinterpret_cast<const float4*>(bias + n0 + nA + j);
            float4 v;
            v.x = acc[i][j + 0] + bv.x; v.y = acc[i][j + 1] + bv.y;
            v.z = acc[i][j + 2] + bv.z; v.w = acc[i][j + 3] + bv.w;
            *reinterpret_cast<float4*>(C + crow + j) = v;
        }
    }
}

// ---------------------------------------------------------------------------
// Persistent GRU scan (one T-chunk of one layer) — R8.
// EXACT R4 skeleton (part-LDS reduce, 3 barriers, tight s_sleep(1) poll,
// contiguous publish — proven 920us; R5-7 variants all regressed), with ONE
// change: topology 32 groups x 8 blocks (was 16x16).
//   - group owns 2 batch rows; block owns 64 h-dims; thread (d=tid&63,
//     kc=tid>>6) holds w_hh[3][D0+d][kc*64..+64] = 192 floats in VGPRs.
//   - relay shrinks: 8 publishers/group (max-straggler), 1024 polled
//     words/block, poll redundancy 8x1024 vs 16x2048 per group.
//   - kc is wave-uniform -> MAC LDS reads are 64-lane broadcasts (free).
// Tagged-word exchange unchanged (relaxed agent atomics only — acquire
// polls invalidate the XCD L2 (R1: 110 GB refetch); 2-slot hbuf
// overwrite-safe by induction; tags unique per layer+step; 0xAA poison
// never matches a tag).
// ---------------------------------------------------------------------------
__global__ __launch_bounds__(512, 2)
void gru_scan(const float* __restrict__ xg,    // chunk-local [64][Tc][1536]
              const float* __restrict__ w_hh,  // [1536][512]
              const float* __restrict__ b_hh,  // [1536]
              float* __restrict__ y,           // [64][1024][512]
              unsigned long long* __restrict__ hbuf, // [32 grp][2 slot][2 b][512]
              int t0, int Tc, int tagbase)
{
    const int tid = threadIdx.x;
    const int grp = blockIdx.x & 31;      // 8 blocks of a group: same XCD
    const int os  = blockIdx.x >> 5;      // output slice 0..7
    const int D0  = os << 6;              // 64 h-dims per block
    const int d   = tid & 63;
    const int kc  = tid >> 6;             // K-chunk 0..7 (64 K each)
    const int bg  = grp << 1;             // 2 batch rows per group

    constexpr int HP = 528;               // h row pad (16B-aligned, 2-way banks)
    __shared__ float h_lds[2][2 * HP];    // [slot][b][D] flat
    __shared__ float part[8 * 392];       // [kc][g*128 + b*64 + d] (384 used)
    __shared__ float hg_red[392];         // 384 used

    // persistent weights: w4[g][j] = w_hh[g*512+D0+d][kc*64 + 4j ..]
    float4 w4[3][16];
#pragma unroll
    for (int g = 0; g < 3; ++g) {
        const float* wr = w_hh + (size_t)(g * 512 + D0 + d) * 512 + kc * 64;
#pragma unroll
        for (int j = 0; j < 16; ++j)
            w4[g][j] = *reinterpret_cast<const float4*>(wr + (j << 2));
    }
    // reduce-phase bias: thread o<384 owns output o = g*128 + b*64 + d
    float bias0 = (tid < 384) ? b_hh[(tid >> 7) * 512 + D0 + (tid & 63)] : 0.f;
    const int b_loc = tid >> 6;           // gate threads (tid<128): row 0..1

    for (int tl = 0; tl < Tc; ++tl) {
        const int tg = t0 + tl;
        float* hl = h_lds[tl & 1];

        // gate threads prefetch this step's xg early (hidden behind poll)
        float xr = 0.f, xz = 0.f, xn = 0.f;
        if (tid < 128) {
            const size_t rowo = ((size_t)(bg + b_loc) * Tc + tl) * 1536 + D0 + d;
            xr = xg[rowo];
            xz = xg[rowo + 512];
            xn = xg[rowo + 1024];
        }

        // stage h_{t-1}[2][512] into LDS: thread owns word tid, tid+512
        if (tg == 0) {
#pragma unroll
            for (int i = 0; i < 2; ++i) {
                int idx = tid + (i << 9);
                hl[(idx >> 9) * HP + (idx & 511)] = 0.f;
            }
        } else {
            const unsigned long long* hsrc =
                hbuf + (size_t)(grp * 2 + ((tg - 1) & 1)) * 1024;
            const unsigned int tagexp = (unsigned int)(tagbase + tl - 1);
            unsigned long long v[2];
            unsigned int pend = 0x3u;
            while (pend) {
#pragma unroll
                for (int i = 0; i < 2; ++i)
                    if (pend & (1u << i))
                        v[i] = __hip_atomic_load(hsrc + tid + (i << 9),
                                __ATOMIC_RELAXED, __HIP_MEMORY_SCOPE_AGENT);
#pragma unroll
                for (int i = 0; i < 2; ++i)
                    if ((pend & (1u << i)) &&
                        (unsigned int)(v[i] >> 32) == tagexp) {
                        int idx = tid + (i << 9);
                        union { unsigned int u; float f; } cv;
                        cv.u = (unsigned int)v[i];
                        hl[(idx >> 9) * HP + (idx & 511)] = cv.f;
                        pend &= ~(1u << i);
                    }
                if (pend) __builtin_amdgcn_s_sleep(1);
            }
        }
        __syncthreads();   // barrier #1: h_{t-1} staged

        // register MAC over this thread's 64-wide K chunk; kc wave-uniform
        // -> both b128 loads per j are full-wave broadcasts.
        float acc[3][2];
#pragma unroll
        for (int g = 0; g < 3; ++g) { acc[g][0] = 0.f; acc[g][1] = 0.f; }
        const float* hb_base = hl + kc * 64;
#pragma unroll
        for (int j = 0; j < 16; ++j) {
            const float4 h0 = *reinterpret_cast<const float4*>(hb_base + (j << 2));
            const float4 h1 = *reinterpret_cast<const float4*>(hb_base + HP + (j << 2));
#pragma unroll
            for (int g = 0; g < 3; ++g) {
                const float4 wv = w4[g][j];
                acc[g][0] = fmaf(wv.x, h0.x, acc[g][0]);
                acc[g][0] = fmaf(wv.y, h0.y, acc[g][0]);
                acc[g][0] = fmaf(wv.z, h0.z, acc[g][0]);
                acc[g][0] = fmaf(wv.w, h0.w, acc[g][0]);
                acc[g][1] = fmaf(wv.x, h1.x, acc[g][1]);
                acc[g][1] = fmaf(wv.y, h1.y, acc[g][1]);
                acc[g][1] = fmaf(wv.z, h1.z, acc[g][1]);
                acc[g][1] = fmaf(wv.w, h1.w, acc[g][1]);
            }
        }
        {
            float* pp = part + kc * 392 + d;
#pragma unroll
            for (int g = 0; g < 3; ++g) {
                pp[g * 128]      = acc[g][0];
                pp[g * 128 + 64] = acc[g][1];
            }
        }
        __syncthreads();   // barrier #2: partials complete

        // reduce over 8 K-chunks: output o = g*128 + b*64 + d
        if (tid < 384) {
            float s = bias0;
#pragma unroll
            for (int q = 0; q < 8; ++q) s += part[q * 392 + tid];
            hg_red[tid] = s;
        }
        __syncthreads();   // barrier #3: hg_red complete

        // gates + state update + tagged publish (fire-and-forget).
        // tid<128: contiguous 512B bursts per batch row.
        if (tid < 128) {
            const float hr = hg_red[tid];
            const float hz = hg_red[128 + tid];
            const float hn = hg_red[256 + tid];
            const int D = D0 + d;
            const float hp = hl[b_loc * HP + D];
            const float r = fast_sigmoid(xr + hr);
            const float z = fast_sigmoid(xz + hz);
            const float nv = fast_tanh(xn + r * hn);
            const float h = (1.f - z) * nv + z * hp;
            union { float f; unsigned int u; } cv; cv.f = h;
            const unsigned long long pk =
                ((unsigned long long)(unsigned int)(tagbase + tl) << 32) | cv.u;
            unsigned long long* hdst =
                hbuf + (size_t)(grp * 2 + (tg & 1)) * 1024 + b_loc * 512 + D;
            __hip_atomic_store(hdst, pk, __ATOMIC_RELAXED,
                               __HIP_MEMORY_SCOPE_AGENT);
            y[((size_t)(bg + b_loc) * T_TOTAL + tg) * HID + D] = h;
        }
        // no trailing barrier: next iter stages into the other h_lds slot;
        // part(t+1) writes happen only after barrier#1(t+1).
    }
}

// ---------------------------------------------------------------------------
extern "C" void kernel_launch(void* const* d_in, const int* in_sizes, int n_in,
                              void* d_out, int out_size, void* d_ws, size_t ws_size,
                              hipStream_t stream)
{
    const float* x       = (const float*)d_in[0];
    const float* w_ih[2] = {(const float*)d_in[1], (const float*)d_in[5]};
    const float* w_hh[2] = {(const float*)d_in[2], (const float*)d_in[6]};
    const float* b_ih[2] = {(const float*)d_in[3], (const float*)d_in[7]};
    const float* b_hh[2] = {(const float*)d_in[4], (const float*)d_in[8]};
    const float* fc_w    = (const float*)d_in[9];
    const float* fc_b    = (const float*)d_in[10];
    float* out = (float*)d_out;

    const size_t Y_BYTES = (size_t)BATCH * T_TOTAL * HID * 4;   // 128 MiB
    const size_t H_BYTES = (size_t)32 * 2 * 2 * 512 * 8;        // 512 KiB (u64)
    int Tc = 256;
    while (Tc > 32) {
        size_t need = (size_t)BATCH * Tc * 1536 * 4 + Y_BYTES + H_BYTES;
        if (need <= ws_size) break;
        Tc >>= 1;
    }

    char* p = (char*)d_ws;
    float* xg_buf = (float*)p;                 p += (size_t)BATCH * Tc * 1536 * 4;
    float* y_buf  = (float*)p;                 p += Y_BYTES;
    unsigned long long* hbuf = (unsigned long long*)p;

    const int nchunks = T_TOTAL / Tc;
    for (int L = 0; L < 2; ++L) {
        const float* A = L ? y_buf : x;
        const int K    = L ? HID : 64;
        for (int c = 0; c < nchunks; ++c) {
            dim3 g1(1536 / 128, (BATCH * Tc) / 128);
            gemm_bt_k<128, 128, 8, 8><<<g1, 256, 0, stream>>>(
                A, w_ih[L], b_ih[L], xg_buf, K, T_TOTAL, Tc, c * Tc, 1536);
            gru_scan<<<256, 512, 0, stream>>>(
                xg_buf, w_hh[L], b_hh[L], y_buf, hbuf,
                c * Tc, Tc, (L << 11) + c * Tc);
        }
    }
    dim3 g2(64 / 64, (BATCH * T_TOTAL) / 128);
    gemm_bt_k<128, 64, 8, 4><<<g2, 256, 0, stream>>>(
        y_buf, fc_w, fc_b, out, HID, BATCH * T_TOTAL, BATCH * T_TOTAL, 0, 64);
}